// Round 3
// baseline (102.435 us; speedup 1.0000x reference)
//
#include <hip/hip_runtime.h>
#include <hip/hip_bf16.h>
#include <stdint.h>

#define QMAX 127.0f

typedef __attribute__((ext_vector_type(8))) short bf16x8;
typedef __attribute__((ext_vector_type(4))) float f32x4;
typedef __attribute__((ext_vector_type(4))) short s16x4;

__device__ inline short quantm(float x, float inv) {
    float q = rintf(x * inv);                // inv = QMAX/absmax (one exact div per row)
    q = fminf(fmaxf(q, -QMAX), QMAX);
    __hip_bfloat16 h = __float2bfloat16(q);  // exact: |q| <= 127 integer
    union { __hip_bfloat16 h; short s; } u;
    u.h = h;
    return u.s;
}

// ---- kernel 1: quantize rhs along axis 0 (per column f), store B^T bf16 [F][K] ----
__global__ void quant_rhs_kernel(const float* __restrict__ rhs,
                                 short* __restrict__ Bt,
                                 float* __restrict__ rscale) {
    const int f = blockIdx.x;      // column 0..511
    const int t = threadIdx.x;     // 0..63
    float v[8];
    float amax = 0.f;
#pragma unroll
    for (int i = 0; i < 8; ++i) {
        v[i] = rhs[(size_t)(t + 64 * i) * 512 + f];
        amax = fmaxf(amax, fabsf(v[i]));
    }
#pragma unroll
    for (int m = 1; m <= 32; m <<= 1)
        amax = fmaxf(amax, __shfl_xor(amax, m, 64));
    const float inv = amax > 0.f ? QMAX / amax : 0.f;
    if (t == 0) rscale[f] = amax > 0.f ? amax * (1.0f / QMAX) : 1.0f;
#pragma unroll
    for (int i = 0; i < 8; ++i)
        Bt[(size_t)f * 512 + t + 64 * i] = quantm(v[i], inv);
}

// ---- kernel 2: fused quant(lhs) + GEMM, one block = 64 rows x full N=512 ----
__global__ __launch_bounds__(512, 4) void fused_kernel(const float* __restrict__ lhs,
                                                       const short* __restrict__ Bt,
                                                       const float* __restrict__ rscale,
                                                       float* __restrict__ out) {
    __shared__ short A[32768];   // [64 rows][512 k] bf16, XOR-swizzled
    __shared__ float lsc[64];

    const int tid  = threadIdx.x;
    const int lane = tid & 63;
    const int wave = tid >> 6;         // 0..7
    const int m0   = blockIdx.x << 6;  // 64 rows per block

    // ---- phase 1: quantize rows m0..m0+63 into LDS (1 div per row) ----
#pragma unroll
    for (int rr = 0; rr < 8; ++rr) {
        const int row = rr * 8 + wave;
        const float* rp = lhs + (size_t)(m0 + row) * 512;
        const float4 a = *(const float4*)(rp + lane * 4);
        const float4 b = *(const float4*)(rp + 256 + lane * 4);
        float amax = fmaxf(fmaxf(fmaxf(fabsf(a.x), fabsf(a.y)), fmaxf(fabsf(a.z), fabsf(a.w))),
                           fmaxf(fmaxf(fabsf(b.x), fabsf(b.y)), fmaxf(fabsf(b.z), fabsf(b.w))));
#pragma unroll
        for (int m = 1; m <= 32; m <<= 1)
            amax = fmaxf(amax, __shfl_xor(amax, m, 64));
        const float inv = amax > 0.f ? QMAX / amax : 0.f;   // one exact div per row
        if (lane == 0) lsc[row] = amax > 0.f ? amax * (1.0f / QMAX) : 1.0f;
        s16x4 o0, o1;
        o0.x = quantm(a.x, inv); o0.y = quantm(a.y, inv);
        o0.z = quantm(a.z, inv); o0.w = quantm(a.w, inv);
        o1.x = quantm(b.x, inv); o1.y = quantm(b.y, inv);
        o1.z = quantm(b.z, inv); o1.w = quantm(b.w, inv);
        char* Ab = (char*)A + row * 1024;
        const int sw = (row & 7) << 4;                    // XOR bits 4..6
        *(s16x4*)(Ab + ((lane * 8) ^ sw))       = o0;     // bytes [0,512)
        *(s16x4*)(Ab + ((512 + lane * 8) ^ sw)) = o1;     // bytes [512,1024)
    }
    __syncthreads();

    // ---- phase 2: GEMM 64x512, wave w owns cols [w*64, w*64+64) ----
    const int lane15  = lane & 15;
    const int laneHi  = lane >> 4;
    const int colBase = wave * 64;

    f32x4 acc[4][4];
#pragma unroll
    for (int i = 0; i < 4; ++i)
#pragma unroll
        for (int j = 0; j < 4; ++j)
            acc[i][j] = (f32x4){0.f, 0.f, 0.f, 0.f};

#pragma unroll
    for (int ks = 0; ks < 16; ++ks) {            // k = ks*32
        const int kbyte = ks * 64 + laneHi * 16;
        bf16x8 af[4], bfr[4];
#pragma unroll
        for (int ni = 0; ni < 4; ++ni) {         // issue global (L2) loads first
            const int col = colBase + ni * 16 + lane15;
            bfr[ni] = *(const bf16x8*)(Bt + (size_t)col * 512 + ks * 32 + laneHi * 8);
        }
#pragma unroll
        for (int mi = 0; mi < 4; ++mi) {
            const int row = mi * 16 + lane15;
            af[mi] = *(const bf16x8*)((const char*)A + row * 1024 + (kbyte ^ ((row & 7) << 4)));
        }
#pragma unroll
        for (int mi = 0; mi < 4; ++mi)
#pragma unroll
            for (int ni = 0; ni < 4; ++ni)
                acc[mi][ni] = __builtin_amdgcn_mfma_f32_16x16x32_bf16(
                    af[mi], bfr[ni], acc[mi][ni], 0, 0, 0);
    }

    // ---- epilogue: C/D layout col=lane&15, row=(lane>>4)*4+reg ----
    float rs[4];
#pragma unroll
    for (int ni = 0; ni < 4; ++ni)
        rs[ni] = rscale[colBase + ni * 16 + lane15];
    const int rg = laneHi * 4;
#pragma unroll
    for (int mi = 0; mi < 4; ++mi) {
#pragma unroll
        for (int r = 0; r < 4; ++r) {
            const int lrow = mi * 16 + rg + r;
            const float ls = lsc[lrow];
            float* op = out + (size_t)(m0 + lrow) * 512;
#pragma unroll
            for (int ni = 0; ni < 4; ++ni)
                op[colBase + ni * 16 + lane15] = acc[mi][ni][r] * ls * rs[ni];
        }
    }
}

extern "C" void kernel_launch(void* const* d_in, const int* in_sizes, int n_in,
                              void* d_out, int out_size, void* d_ws, size_t ws_size,
                              hipStream_t stream) {
    const float* lhs = (const float*)d_in[0];   // [4,16384,512] f32
    const float* rhs = (const float*)d_in[1];   // [512,512] f32
    float* out = (float*)d_out;                 // [4,16384,512] f32

    char* ws = (char*)d_ws;
    short* Bt     = (short*)ws;                 // 512KB
    float* rscale = (float*)(ws + 524288);

    const int rows = in_sizes[0] / 512;         // 65536

    quant_rhs_kernel<<<512, 64, 0, stream>>>(rhs, Bt, rscale);
    fused_kernel<<<rows / 64, 512, 0, stream>>>(lhs, Bt, rscale, out);
}